// Round 4
// baseline (125.965 us; speedup 1.0000x reference)
//
#include <hip/hip_runtime.h>

#define IN_F 8192
#define OUT_F 8192
#define NNZ 262144
#define EPS 1e-7f
#define SLOTS 80  // rows ~ Poisson(32); 80 = +8.5 sigma, overflow-guarded

// ---------------- Workspace layout (d_ws) ----------------
// [0)    tT   : IN_F*64 floats        = 2 MB
// [2MB)  cnt  : OUT_F ints            = 32 KB
// [2MB+64K) sCol : OUT_F*SLOTS ints   = 2.5 MB
// [8MB)  sW   : OUT_F*SLOTS float8    = 21 MB
#define WS_TT   0
#define WS_CNT  (2u << 20)
#define WS_SCOL ((2u << 20) + (64u << 10))
#define WS_SW   (8u << 20)

// K1: blocks [0,128) do tanh+transpose; blocks [128,384) slot-scatter edges.
__global__ __launch_bounds__(256) void prep_kernel(
    const float* __restrict__ x, const float* __restrict__ w,
    const int* __restrict__ rows, const int* __restrict__ cols,
    float* __restrict__ tT, int* __restrict__ cnt,
    int* __restrict__ sCol, float4* __restrict__ sW) {
  __shared__ float lds[64 * 65];
  const int tid = threadIdx.x;
  if (blockIdx.x < 128) {
    const int f0 = blockIdx.x * 64;
#pragma unroll
    for (int i = 0; i < 16; ++i) {
      int idx = tid + i * 256;
      int f = idx & 63;  // fast -> coalesced global read
      int b = idx >> 6;
      float v = tanhf(x[b * IN_F + f0 + f]);
      v = fminf(fmaxf(v, -1.0f + EPS), 1.0f - EPS);
      lds[f * 65 + b] = v;
    }
    __syncthreads();
#pragma unroll
    for (int i = 0; i < 16; ++i) {
      int idx = tid + i * 256;
      int b = idx & 63;  // fast -> coalesced global write
      int f = idx >> 6;
      tT[(f0 + f) * 64 + b] = lds[f * 65 + b];
    }
  } else {
    // 4 edges per thread; copy (col, weights) into the row's slot bin.
    const int i = (blockIdx.x - 128) * 256 + tid;
    const int4 r = ((const int4*)rows)[i];
    const int4 c = ((const int4*)cols)[i];
    const float4* w4 = (const float4*)w;  // 2 float4 per edge, coalesced read
    const int e = i * 4;
    {
      int p = atomicAdd(&cnt[r.x], 1);
      if (p < SLOTS) { int s = r.x * SLOTS + p; sCol[s] = c.x;
        sW[2 * s] = w4[2 * e + 0]; sW[2 * s + 1] = w4[2 * e + 1]; }
    }
    {
      int p = atomicAdd(&cnt[r.y], 1);
      if (p < SLOTS) { int s = r.y * SLOTS + p; sCol[s] = c.y;
        sW[2 * s] = w4[2 * e + 2]; sW[2 * s + 1] = w4[2 * e + 3]; }
    }
    {
      int p = atomicAdd(&cnt[r.z], 1);
      if (p < SLOTS) { int s = r.z * SLOTS + p; sCol[s] = c.z;
        sW[2 * s] = w4[2 * e + 4]; sW[2 * s + 1] = w4[2 * e + 5]; }
    }
    {
      int p = atomicAdd(&cnt[r.w], 1);
      if (p < SLOTS) { int s = r.w * SLOTS + p; sCol[s] = c.w;
        sW[2 * s] = w4[2 * e + 6]; sW[2 * s + 1] = w4[2 * e + 7]; }
    }
  }
}

// Per-edge Chebyshev dot; slot is wave-uniform -> scalar weight loads.
__device__ __forceinline__ float cheb_dot(const float* __restrict__ tT,
                                          const float4* __restrict__ sW,
                                          int slot, int ci, int lane) {
  const float4 wa = sW[2 * slot];      // wave-uniform, contiguous slots
  const float4 wb = sW[2 * slot + 1];
  const float t = tT[((unsigned)ci << 6) + lane];  // coalesced 256B
  const float t2 = t + t;
  float Tm = t;
  float Tc = fmaf(t2, t, -1.0f);            // T2
  float acc = fmaf(wa.y, t, wa.x);
  acc = fmaf(wa.z, Tc, acc);
  float Tn = fmaf(t2, Tc, -Tm);             // T3
  acc = fmaf(wa.w, Tn, acc);
  Tm = Tc; Tc = Tn;
  Tn = fmaf(t2, Tc, -Tm);                   // T4
  acc = fmaf(wb.x, Tn, acc);
  Tm = Tc; Tc = Tn;
  Tn = fmaf(t2, Tc, -Tm);                   // T5
  acc = fmaf(wb.y, Tn, acc);
  Tm = Tc; Tc = Tn;
  Tn = fmaf(t2, Tc, -Tm);                   // T6
  acc = fmaf(wb.z, Tn, acc);
  Tm = Tc; Tc = Tn;
  Tn = fmaf(t2, Tc, -Tm);                   // T7
  acc = fmaf(wb.w, Tn, acc);
  return acc;
}

// K2: block owns 32 rows; wave per row (x8); LDS tile; coalesced y write.
__global__ __launch_bounds__(256) void gather_kernel(
    const float* __restrict__ tT, const int* __restrict__ cnt,
    const int* __restrict__ sCol, const float4* __restrict__ sW,
    float* __restrict__ y) {
  __shared__ float tile[32 * 65];
  const int tid = threadIdx.x;
  const int lane = tid & 63;
  const int wv = tid >> 6;
  const int r0 = blockIdx.x * 32;
  for (int rr = wv; rr < 32; rr += 4) {
    const int row = __builtin_amdgcn_readfirstlane(r0 + rr);
    const int n = min(__builtin_amdgcn_readfirstlane(cnt[row]), SLOTS);
    const int base = row * SLOTS;
    float acc = 0.0f;
    for (int s = 0; s < n; s += 64) {
      int cv = 0;
      if (s + lane < n) cv = sCol[base + s + lane];  // coalesced
      const int m = min(64, n - s);
      int i = 0;
      for (; i + 4 <= m; i += 4) {
        const int c0 = __builtin_amdgcn_readlane(cv, i);
        const int c1 = __builtin_amdgcn_readlane(cv, i + 1);
        const int c2 = __builtin_amdgcn_readlane(cv, i + 2);
        const int c3 = __builtin_amdgcn_readlane(cv, i + 3);
        const int sl = base + s + i;
        const float a0 = cheb_dot(tT, sW, sl + 0, c0, lane);
        const float a1 = cheb_dot(tT, sW, sl + 1, c1, lane);
        const float a2 = cheb_dot(tT, sW, sl + 2, c2, lane);
        const float a3 = cheb_dot(tT, sW, sl + 3, c3, lane);
        acc += (a0 + a1) + (a2 + a3);
      }
      for (; i < m; ++i) {
        const int c0 = __builtin_amdgcn_readlane(cv, i);
        acc += cheb_dot(tT, sW, base + s + i, c0, lane);
      }
    }
    tile[rr * 65 + lane] = acc;  // 2-way bank alias: free
  }
  __syncthreads();
#pragma unroll
  for (int it = 0; it < 8; ++it) {
    const int idx = tid + it * 256;
    const int rr = idx & 31;  // fast -> coalesced y write
    const int b = idx >> 5;
    y[b * OUT_F + r0 + rr] = tile[rr * 65 + b];
  }
}

extern "C" void kernel_launch(void* const* d_in, const int* in_sizes, int n_in,
                              void* d_out, int out_size, void* d_ws, size_t ws_size,
                              hipStream_t stream) {
  const float* x    = (const float*)d_in[0];
  const float* w    = (const float*)d_in[1];
  const int*   rows = (const int*)d_in[2];
  const int*   cols = (const int*)d_in[3];
  float* y = (float*)d_out;

  char* ws = (char*)d_ws;
  float*  tT   = (float*)(ws + WS_TT);
  int*    cnt  = (int*)(ws + WS_CNT);
  int*    sCol = (int*)(ws + WS_SCOL);
  float4* sW   = (float4*)(ws + WS_SW);

  hipMemsetAsync(cnt, 0, OUT_F * sizeof(int), stream);
  prep_kernel<<<384, 256, 0, stream>>>(x, w, rows, cols, tT, cnt, sCol, sW);
  gather_kernel<<<OUT_F / 32, 256, 0, stream>>>(tT, cnt, sCol, sW, y);
}

// Round 5
// 102.790 us; speedup vs baseline: 1.2255x; 1.2255x over previous
//
#include <hip/hip_runtime.h>

#define IN_F 8192
#define OUT_F 8192
#define NNZ 262144
#define EPS 1e-7f
#define SLOTS 80  // rows ~ Poisson(32); 80 = +8.5 sigma, overflow-guarded

// ---------------- Workspace layout (d_ws) ----------------
// [0)       tT   : IN_F*64 floats      = 2 MB
// [2MB)     cnt  : OUT_F ints          = 32 KB
// [2MB+64K) sCol : OUT_F*SLOTS ints    = 2.5 MB
// [8MB)     sW   : OUT_F*SLOTS float8  = 21 MB
#define WS_TT   0
#define WS_CNT  (2u << 20)
#define WS_SCOL ((2u << 20) + (64u << 10))
#define WS_SW   (8u << 20)

// K1: blocks [0,128) tanh+transpose; blocks [128,1152) slot-scatter, 1 edge/thread.
__global__ __launch_bounds__(256) void prep_kernel(
    const float* __restrict__ x, const float* __restrict__ w,
    const int* __restrict__ rows, const int* __restrict__ cols,
    float* __restrict__ tT, int* __restrict__ cnt,
    int* __restrict__ sCol, float4* __restrict__ sW) {
  const int tid = threadIdx.x;
  if (blockIdx.x < 128) {
    __shared__ float lds[64 * 65];
    const int f0 = blockIdx.x * 64;
#pragma unroll
    for (int i = 0; i < 16; ++i) {
      int idx = tid + i * 256;
      int f = idx & 63;  // fast -> coalesced global read
      int b = idx >> 6;
      float v = tanhf(x[b * IN_F + f0 + f]);
      v = fminf(fmaxf(v, -1.0f + EPS), 1.0f - EPS);
      lds[f * 65 + b] = v;
    }
    __syncthreads();
#pragma unroll
    for (int i = 0; i < 16; ++i) {
      int idx = tid + i * 256;
      int b = idx & 63;  // fast -> coalesced global write
      int f = idx >> 6;
      tT[(f0 + f) * 64 + b] = lds[f * 65 + b];
    }
  } else {
    const int e = (blockIdx.x - 128) * 256 + tid;  // 1 edge per thread
    const int r = rows[e];
    const int c = cols[e];
    const float4* w4 = (const float4*)w;  // 2 float4 per edge, coalesced
    const float4 wa = w4[2 * e];
    const float4 wb = w4[2 * e + 1];
    const int p = atomicAdd(&cnt[r], 1);
    if (p < SLOTS) {
      const int s = r * SLOTS + p;
      sCol[s] = c;
      sW[2 * s] = wa;
      sW[2 * s + 1] = wb;
    }
  }
}

// Per-edge Chebyshev dot; slot is wave-uniform -> scalar weight loads.
__device__ __forceinline__ float cheb_dot(const float* __restrict__ tT,
                                          const float4* __restrict__ sW,
                                          int slot, int ci, int lane) {
  const float4 wa = sW[2 * slot];      // wave-uniform, contiguous slots
  const float4 wb = sW[2 * slot + 1];
  const float t = tT[((unsigned)ci << 6) + lane];  // coalesced 256B
  const float t2 = t + t;
  float Tm = t;
  float Tc = fmaf(t2, t, -1.0f);            // T2
  float acc = fmaf(wa.y, t, wa.x);
  acc = fmaf(wa.z, Tc, acc);
  float Tn = fmaf(t2, Tc, -Tm);             // T3
  acc = fmaf(wa.w, Tn, acc);
  Tm = Tc; Tc = Tn;
  Tn = fmaf(t2, Tc, -Tm);                   // T4
  acc = fmaf(wb.x, Tn, acc);
  Tm = Tc; Tc = Tn;
  Tn = fmaf(t2, Tc, -Tm);                   // T5
  acc = fmaf(wb.y, Tn, acc);
  Tm = Tc; Tc = Tn;
  Tn = fmaf(t2, Tc, -Tm);                   // T6
  acc = fmaf(wb.z, Tn, acc);
  Tm = Tc; Tc = Tn;
  Tn = fmaf(t2, Tc, -Tm);                   // T7
  acc = fmaf(wb.w, Tn, acc);
  return acc;
}

// K2: block owns 4 rows (wave per row); 2048 blocks -> 8 blocks/CU.
__global__ __launch_bounds__(256) void gather_kernel(
    const float* __restrict__ tT, const int* __restrict__ cnt,
    const int* __restrict__ sCol, const float4* __restrict__ sW,
    float* __restrict__ y) {
  __shared__ float tile[4 * 65];
  const int tid = threadIdx.x;
  const int lane = tid & 63;
  const int wv = tid >> 6;
  const int r0 = blockIdx.x * 4;
  const int row = __builtin_amdgcn_readfirstlane(r0 + wv);
  const int n = min(__builtin_amdgcn_readfirstlane(cnt[row]), SLOTS);
  const int base = row * SLOTS;
  float acc = 0.0f;
  for (int s = 0; s < n; s += 64) {  // at most 2 iterations (n <= 80)
    int cv = 0;
    if (s + lane < n) cv = sCol[base + s + lane];  // coalesced
    const int m = min(64, n - s);
    int i = 0;
    for (; i + 4 <= m; i += 4) {
      const int c0 = __builtin_amdgcn_readlane(cv, i);
      const int c1 = __builtin_amdgcn_readlane(cv, i + 1);
      const int c2 = __builtin_amdgcn_readlane(cv, i + 2);
      const int c3 = __builtin_amdgcn_readlane(cv, i + 3);
      const int sl = base + s + i;
      const float a0 = cheb_dot(tT, sW, sl + 0, c0, lane);
      const float a1 = cheb_dot(tT, sW, sl + 1, c1, lane);
      const float a2 = cheb_dot(tT, sW, sl + 2, c2, lane);
      const float a3 = cheb_dot(tT, sW, sl + 3, c3, lane);
      acc += (a0 + a1) + (a2 + a3);
    }
    for (; i < m; ++i) {
      const int c0 = __builtin_amdgcn_readlane(cv, i);
      acc += cheb_dot(tT, sW, base + s + i, c0, lane);
    }
  }
  tile[wv * 65 + lane] = acc;
  __syncthreads();
  // 256 threads write the 4x64 tile; rr fast -> 16B-contiguous segments.
  const int rr = tid & 3;
  const int b = tid >> 2;
  y[b * OUT_F + r0 + rr] = tile[rr * 65 + b];
}

extern "C" void kernel_launch(void* const* d_in, const int* in_sizes, int n_in,
                              void* d_out, int out_size, void* d_ws, size_t ws_size,
                              hipStream_t stream) {
  const float* x    = (const float*)d_in[0];
  const float* w    = (const float*)d_in[1];
  const int*   rows = (const int*)d_in[2];
  const int*   cols = (const int*)d_in[3];
  float* y = (float*)d_out;

  char* ws = (char*)d_ws;
  float*  tT   = (float*)(ws + WS_TT);
  int*    cnt  = (int*)(ws + WS_CNT);
  int*    sCol = (int*)(ws + WS_SCOL);
  float4* sW   = (float4*)(ws + WS_SW);

  hipMemsetAsync(cnt, 0, OUT_F * sizeof(int), stream);
  prep_kernel<<<128 + NNZ / 256, 256, 0, stream>>>(x, w, rows, cols, tT, cnt, sCol, sW);
  gather_kernel<<<OUT_F / 4, 256, 0, stream>>>(tT, cnt, sCol, sW, y);
}